// Round 9
// baseline (359.614 us; speedup 1.0000x reference)
//
#include <hip/hip_runtime.h>
#include <math.h>

#define NHEAD 16
#define BB 2
#define SS 2048
#define BS (BB*SS)

typedef _Float16 f16x8 __attribute__((ext_vector_type(8)));
typedef float f32x4 __attribute__((ext_vector_type(4)));

__device__ __forceinline__ unsigned short f2h(float f) {
    _Float16 h = (_Float16)f;                       // RNE
    return __builtin_bit_cast(unsigned short, h);
}

// ---------------------------------------------------------------------------
// Batched f32 -> f16 conversion (x + 8 weight matrices), one dispatch.
// ---------------------------------------------------------------------------
struct CJobs { const float* src[9]; unsigned short* dst[9]; int n4[9]; };

__global__ void convert_f16(CJobs js)
{
    const int j = blockIdx.y;
    const float* __restrict__ s = js.src[j];
    unsigned short* __restrict__ d = js.dst[j];
    const int n4 = js.n4[j];
    for (int i = blockIdx.x * 256 + threadIdx.x; i < n4; i += gridDim.x * 256) {
        const float4 v = ((const float4*)s)[i];
        ushort4 o;
        o.x = f2h(v.x); o.y = f2h(v.y); o.z = f2h(v.z); o.w = f2h(v.w);
        ((ushort4*)d)[i] = o;
    }
}

#define INVF_C 0.4152410118609203f   /* log2(10000)/32 */

// ---------------------------------------------------------------------------
// Fused latent projections: x(4096x1024) @ {Wkv^T(256) | Wq^T(512) | Wkr^T(64)}.
// Grid (13, 64), 128 threads = 2 waves; wave w computes M-frags {2w, 2w+1}.
// Tiles 0-3 -> c_vk, 4-11 -> c_q, 12 -> rope(k_rope).
// LDS row stride 40 shorts (80B): frag b128 reads hit the 8-touch/bank floor.
// A frag: row=lane&15, k=(lane>>4)*8+j ; B frag: col=lane&15 (W row = out col).
// ---------------------------------------------------------------------------
__launch_bounds__(128)
__global__ void gemm_latent(const unsigned short* __restrict__ Xf,
                            const unsigned short* __restrict__ Wkv, const float* __restrict__ bkv,
                            const unsigned short* __restrict__ Wq,  const float* __restrict__ bq,
                            const unsigned short* __restrict__ Wkr, const float* __restrict__ bkr,
                            unsigned short* __restrict__ c_vk, unsigned short* __restrict__ c_q,
                            unsigned short* __restrict__ k_rope)
{
    __shared__ __align__(16) unsigned short As[64 * 40];
    __shared__ __align__(16) unsigned short Bs[64 * 40];
    const int tid = threadIdx.x;
    const int wave = tid >> 6, lane = tid & 63;
    const int g = lane >> 4, r = lane & 15;
    const int t = blockIdx.x;
    const int m0 = blockIdx.y * 64;

    const unsigned short* W; const float* bias; int n0seg;
    if (t < 4)       { W = Wkv; bias = bkv; n0seg = t * 64; }
    else if (t < 12) { W = Wq;  bias = bq;  n0seg = (t - 4) * 64; }
    else             { W = Wkr; bias = bkr; n0seg = 0; }

    f32x4 acc[2][4];
    #pragma unroll
    for (int i = 0; i < 2; ++i)
        #pragma unroll
        for (int j = 0; j < 4; ++j) acc[i][j] = (f32x4){0.f, 0.f, 0.f, 0.f};

    for (int k0 = 0; k0 < 1024; k0 += 32) {
        __syncthreads();
        #pragma unroll
        for (int c = tid; c < 256; c += 128) {
            const int row = c >> 2, o8 = (c & 3) * 8;
            *(uint4*)&As[row * 40 + o8] = *(const uint4*)(Xf + (size_t)(m0 + row) * 1024 + k0 + o8);
            *(uint4*)&Bs[row * 40 + o8] = *(const uint4*)(W + (size_t)(n0seg + row) * 1024 + k0 + o8);
        }
        __syncthreads();
        f16x8 af[2];
        #pragma unroll
        for (int ml = 0; ml < 2; ++ml)
            af[ml] = *(const f16x8*)&As[((wave * 2 + ml) * 16 + r) * 40 + g * 8];
        #pragma unroll
        for (int ni = 0; ni < 4; ++ni) {
            const f16x8 bfr = *(const f16x8*)&Bs[(ni * 16 + r) * 40 + g * 8];
            #pragma unroll
            for (int ml = 0; ml < 2; ++ml)
                acc[ml][ni] = __builtin_amdgcn_mfma_f32_16x16x32_f16(af[ml], bfr, acc[ml][ni], 0, 0, 0);
        }
    }

    if (t < 12) {
        unsigned short* dst; int N;
        if (t < 4) { dst = c_vk; N = 256; } else { dst = c_q; N = 512; }
        #pragma unroll
        for (int ml = 0; ml < 2; ++ml)
            #pragma unroll
            for (int ni = 0; ni < 4; ++ni) {
                const int n = n0seg + ni * 16 + r;
                const float bi = bias[n];
                #pragma unroll
                for (int e = 0; e < 4; ++e) {
                    const int m = m0 + (wave * 2 + ml) * 16 + g * 4 + e;
                    dst[(size_t)m * N + n] = f2h(acc[ml][ni][e] + bi);
                }
            }
    } else {
        // k_rope: rotate pairs (i, i+32), write once per (b,s): (B,S,64)
        const int b = m0 >> 11;
        #pragma unroll
        for (int ml = 0; ml < 2; ++ml)
            #pragma unroll
            for (int ni = 0; ni < 2; ++ni) {
                const int i = ni * 16 + r;
                const float b1 = bias[i], b2 = bias[i + 32];
                const float invf = exp2f(-(float)i * INVF_C);
                #pragma unroll
                for (int e = 0; e < 4; ++e) {
                    const int m = m0 + (wave * 2 + ml) * 16 + g * 4 + e;
                    const int s = m & 2047;
                    float sn, cs;
                    sincosf((float)s * invf, &sn, &cs);
                    const float t1 = acc[ml][ni][e] + b1;
                    const float t2 = acc[ml][ni + 2][e] + b2;
                    unsigned short* o = k_rope + ((size_t)b * 2048 + s) * 64;
                    o[i]      = f2h(t1 * cs - t2 * sn);
                    o[i + 32] = f2h(t1 * sn + t2 * cs);
                }
            }
    }
}

// ---------------------------------------------------------------------------
// 4-wave 128x128 MFMA GEMM core + mode-templated epilogues.
// waves: wm = wave>>1 (M half), wn = wave&1 (N half); per-wave 64x64 out.
// MODE 0: segA -> k_head (B*H,S,64); segB -> v_t (B*H,64,S) transposed
// MODE 2: segA -> q_full dims 0..63; segB -> q_full dims 64..127 (rope)
// MODE 4: f32 row-major out (final projection)
// ---------------------------------------------------------------------------
template<int MODE>
__launch_bounds__(256)
__global__ void gemm128(const unsigned short* __restrict__ X,
                        const unsigned short* __restrict__ WA,
                        const float* __restrict__ biasA,
                        const unsigned short* __restrict__ WB,
                        const float* __restrict__ biasB,
                        void* __restrict__ Yv, void* __restrict__ Yv2,
                        int K, int nseg_blocks)
{
    __shared__ __align__(16) unsigned short As[128 * 40];
    __shared__ __align__(16) unsigned short Bs[128 * 40];
    const int tid = threadIdx.x;
    const int wave = tid >> 6, lane = tid & 63;
    const int g = lane >> 4, r = lane & 15;
    const int wm = wave >> 1, wn = wave & 1;
    const int m0 = blockIdx.y * 128;
    const bool segA = ((int)blockIdx.x < nseg_blocks);
    const int n0seg = (segA ? blockIdx.x : blockIdx.x - nseg_blocks) * 128;
    const unsigned short* W = segA ? WA : WB;
    const float* bias = segA ? biasA : biasB;

    f32x4 acc[4][4];
    #pragma unroll
    for (int i = 0; i < 4; ++i)
        #pragma unroll
        for (int j = 0; j < 4; ++j) acc[i][j] = (f32x4){0.f, 0.f, 0.f, 0.f};

    for (int k0 = 0; k0 < K; k0 += 32) {
        __syncthreads();
        #pragma unroll
        for (int c = tid; c < 512; c += 256) {
            const int row = c >> 2, o8 = (c & 3) * 8;
            *(uint4*)&As[row * 40 + o8] = *(const uint4*)(X + (size_t)(m0 + row) * K + k0 + o8);
            *(uint4*)&Bs[row * 40 + o8] = *(const uint4*)(W + (size_t)(n0seg + row) * K + k0 + o8);
        }
        __syncthreads();
        f16x8 af[4];
        #pragma unroll
        for (int mi = 0; mi < 4; ++mi)
            af[mi] = *(const f16x8*)&As[(wm * 64 + mi * 16 + r) * 40 + g * 8];
        #pragma unroll
        for (int ni = 0; ni < 4; ++ni) {
            const f16x8 bfr = *(const f16x8*)&Bs[(wn * 64 + ni * 16 + r) * 40 + g * 8];
            #pragma unroll
            for (int mi = 0; mi < 4; ++mi)
                acc[mi][ni] = __builtin_amdgcn_mfma_f32_16x16x32_f16(af[mi], bfr, acc[mi][ni], 0, 0, 0);
        }
    }

    const int b = m0 >> 11;   // 128 | 2048 so a tile never crosses batches

    if ((MODE == 0 || MODE == 2) && segA) {
        // scalar head-split writes: k_head or q_full dims 0..63
        unsigned short* dst = (unsigned short*)Yv;
        const int ldo = (MODE == 0) ? 64 : 128;
        #pragma unroll
        for (int mi = 0; mi < 4; ++mi)
            #pragma unroll
            for (int ni = 0; ni < 4; ++ni) {
                const int n = n0seg + wn * 64 + ni * 16 + r;
                const int h = n >> 6, d = n & 63;
                const float bi = bias[n];
                #pragma unroll
                for (int e = 0; e < 4; ++e) {
                    const int m = m0 + wm * 64 + mi * 16 + g * 4 + e;
                    const int s = m & 2047;
                    dst[((size_t)(b * 16 + h) * 2048 + s) * ldo + d] = f2h(acc[mi][ni][e] + bi);
                }
            }
    } else if (MODE == 0 || MODE == 2) {
        if (MODE == 0) {
            // v_t (B*H, 64, S) transposed epilogue
            unsigned short* vt = (unsigned short*)Yv2;
            #pragma unroll
            for (int mi = 0; mi < 4; ++mi)
                #pragma unroll
                for (int ni = 0; ni < 4; ++ni) {
                    const int n = n0seg + wn * 64 + ni * 16 + r;
                    const int h = n >> 6, d = n & 63;
                    const float bi = bias[n];
                    const int s0 = (m0 + wm * 64 + mi * 16 + g * 4) & 2047;
                    ushort4 o;
                    o.x = f2h(acc[mi][ni][0] + bi);
                    o.y = f2h(acc[mi][ni][1] + bi);
                    o.z = f2h(acc[mi][ni][2] + bi);
                    o.w = f2h(acc[mi][ni][3] + bi);
                    *(ushort4*)&vt[((size_t)(b * 16 + h) * 64 + d) * 2048 + s0] = o;
                }
        } else {
            // q rope epilogue into q_full dims 64..127
            unsigned short* qd = (unsigned short*)Yv;
            const int h = (n0seg + wn * 64) >> 6;   // one head per wave
            #pragma unroll
            for (int mi = 0; mi < 4; ++mi)
                #pragma unroll
                for (int ni = 0; ni < 2; ++ni) {
                    const int i = ni * 16 + r;
                    const float b1 = bias[n0seg + wn * 64 + i];
                    const float b2 = bias[n0seg + wn * 64 + i + 32];
                    const float invf = exp2f(-(float)i * INVF_C);
                    #pragma unroll
                    for (int e = 0; e < 4; ++e) {
                        const int m = m0 + wm * 64 + mi * 16 + g * 4 + e;
                        const int s = m & 2047;
                        float sn, cs;
                        sincosf((float)s * invf, &sn, &cs);
                        const float t1 = acc[mi][ni][e] + b1;
                        const float t2 = acc[mi][ni + 2][e] + b2;
                        unsigned short* base = qd + ((size_t)(b * 16 + h) * 2048 + s) * 128;
                        base[64 + i] = f2h(t1 * cs - t2 * sn);
                        base[96 + i] = f2h(t1 * sn + t2 * cs);
                    }
                }
        }
    } else {
        // MODE 4: plain f32 row-major (N = 1024)
        float* Y = (float*)Yv;
        #pragma unroll
        for (int mi = 0; mi < 4; ++mi)
            #pragma unroll
            for (int ni = 0; ni < 4; ++ni) {
                const int n = n0seg + wn * 64 + ni * 16 + r;
                const float bi = bias[n];
                #pragma unroll
                for (int e = 0; e < 4; ++e) {
                    const int m = m0 + wm * 64 + mi * 16 + g * 4 + e;
                    Y[(size_t)m * 1024 + n] = acc[mi][ni][e] + bi;
                }
            }
    }
}

// ---------------------------------------------------------------------------
// Causal flash attention, MFMA f16, SWAPPED operands, 32 q-rows per wave.
// Grid (16, 32), 256 thr, 3 blocks/CU.  Block q-tile = 128 rows; wave owns
// rows q0+wave*32+{r, 16+r}.  QK^T loop loads each K frag ONCE and feeds
// both halves (explicit sharing; 16 b128/tile/wave).  Softmax in log2
// domain: scale2 = scale*log2(e), p = exp2(s2 - m2) == e^((s-m)*scale);
// masked = -1e9 -> exp2 -> 0.  PV = mfma(V^T_frag, P_frag) -> O^T.
// Causal balance: qt -> 15-qt for batch 1 (dispatch heuristic only).
// T14 async-stage: next tile's K/V loads issue right after the barrier.
// ---------------------------------------------------------------------------
__launch_bounds__(256, 3)
__global__ void attn_mfma(const unsigned short* __restrict__ qf,
                          const unsigned short* __restrict__ kh,
                          const unsigned short* __restrict__ krope,
                          const unsigned short* __restrict__ vt,
                          unsigned short* __restrict__ out)
{
    __shared__ __align__(16) unsigned short Ks[64 * 136];
    __shared__ __align__(16) unsigned short Vs[64 * 72];
    __shared__ __align__(16) unsigned short Ps[128 * 72];

    const int tid = threadIdx.x;
    const int wave = tid >> 6, lane = tid & 63;
    const int g = lane >> 4, r = lane & 15;
    const int bh = blockIdx.y;
    const int b = bh >> 4, h = bh & 15;
    const int qt = ((bh >> 4) & 1) ? (int)(gridDim.x - 1 - blockIdx.x) : (int)blockIdx.x;
    const int q0 = qt * 128;
    const float scale2 = 0.08838834764831845f * 1.4426950408889634f;  // /sqrt(128) * log2(e)

    const unsigned short* khb = kh + (size_t)bh * 2048 * 64;
    const unsigned short* krb = krope + (size_t)b * 2048 * 64;
    const unsigned short* vb = vt + (size_t)bh * 64 * 2048;

    // prefetch tile 0 into regs
    uint4 kpre[4], vpre[2];
    #pragma unroll
    for (int i = 0; i < 4; ++i) {
        const int c = tid + i * 256, row = c >> 4, ch = c & 15;
        kpre[i] = (ch < 8) ? *(const uint4*)(khb + (size_t)row * 64 + ch * 8)
                           : *(const uint4*)(krb + (size_t)row * 64 + (ch - 8) * 8);
    }
    #pragma unroll
    for (int i = 0; i < 2; ++i) {
        const int c = tid + i * 256, d = c >> 3, o8 = (c & 7) * 8;
        vpre[i] = *(const uint4*)(vb + (size_t)d * 2048 + o8);
    }

    // Q frags for both halves, direct from global
    const int qa = q0 + wave * 32 + r;
    const int qb = qa + 16;
    const unsigned short* qra = qf + ((size_t)bh * 2048 + qa) * 128;
    const unsigned short* qrb = qf + ((size_t)bh * 2048 + qb) * 128;
    f16x8 aqA[4], aqB[4];
    #pragma unroll
    for (int ks = 0; ks < 4; ++ks) {
        aqA[ks] = *(const f16x8*)(qra + ks * 32 + g * 8);
        aqB[ks] = *(const f16x8*)(qrb + ks * 32 + g * 8);
    }

    float mA = -1e30f, lA = 0.f, mB = -1e30f, lB = 0.f;
    f32x4 accA[4], accB[4];
    #pragma unroll
    for (int nf = 0; nf < 4; ++nf) {
        accA[nf] = (f32x4){0.f, 0.f, 0.f, 0.f};
        accB[nf] = (f32x4){0.f, 0.f, 0.f, 0.f};
    }

    const int rowA = (wave * 32 + r) * 72;        // Ps row bases (shorts)
    const int rowB = (wave * 32 + 16 + r) * 72;

    const int kmax = q0 + 64;                     // last tile start
    for (int k0 = 0; k0 <= kmax; k0 += 64) {
        // write prefetched tile to LDS
        #pragma unroll
        for (int i = 0; i < 4; ++i) {
            const int c = tid + i * 256, row = c >> 4, ch = c & 15;
            *(uint4*)&Ks[row * 136 + ch * 8] = kpre[i];
        }
        #pragma unroll
        for (int i = 0; i < 2; ++i) {
            const int c = tid + i * 256, d = c >> 3, o8 = (c & 7) * 8;
            *(uint4*)&Vs[d * 72 + o8] = vpre[i];
        }
        __syncthreads();

        // issue next tile's loads (overlap with compute below)
        if (k0 <= q0) {
            const int kn = k0 + 64;
            #pragma unroll
            for (int i = 0; i < 4; ++i) {
                const int c = tid + i * 256, row = c >> 4, ch = c & 15;
                kpre[i] = (ch < 8) ? *(const uint4*)(khb + (size_t)(kn + row) * 64 + ch * 8)
                                   : *(const uint4*)(krb + (size_t)(kn + row) * 64 + (ch - 8) * 8);
            }
            #pragma unroll
            for (int i = 0; i < 2; ++i) {
                const int c = tid + i * 256, d = c >> 3, o8 = (c & 7) * 8;
                vpre[i] = *(const uint4*)(vb + (size_t)d * 2048 + kn + o8);
            }
        }

        // QK^T, both halves sharing each K frag (loaded once)
        f32x4 scA[4], scB[4];
        #pragma unroll
        for (int nf = 0; nf < 4; ++nf) {
            scA[nf] = (f32x4){0.f, 0.f, 0.f, 0.f};
            scB[nf] = (f32x4){0.f, 0.f, 0.f, 0.f};
            #pragma unroll
            for (int ks = 0; ks < 4; ++ks) {
                const f16x8 bk = *(const f16x8*)&Ks[(nf * 16 + r) * 136 + ks * 32 + g * 8];
                scA[nf] = __builtin_amdgcn_mfma_f32_16x16x32_f16(bk, aqA[ks], scA[nf], 0, 0, 0);
                scB[nf] = __builtin_amdgcn_mfma_f32_16x16x32_f16(bk, aqB[ks], scB[nf], 0, 0, 0);
            }
        }

        // ------- half A softmax (log2 domain, scores masked in place) -------
        {
            float mx = -1e30f;
            #pragma unroll
            for (int nf = 0; nf < 4; ++nf)
                #pragma unroll
                for (int e = 0; e < 4; ++e) {
                    float v = scA[nf][e] * scale2;
                    if (k0 + nf * 16 + 4 * g + e > qa) v = -1.0e9f;
                    scA[nf][e] = v;
                    mx = fmaxf(mx, v);
                }
            mx = fmaxf(mx, __shfl_xor(mx, 16));
            mx = fmaxf(mx, __shfl_xor(mx, 32));
            const float mnew = fmaxf(mA, mx);
            const float fac = exp2f(mA - mnew);
            float rs = 0.f;
            #pragma unroll
            for (int nf = 0; nf < 4; ++nf) {
                const float p0 = exp2f(scA[nf][0] - mnew);
                const float p1 = exp2f(scA[nf][1] - mnew);
                const float p2 = exp2f(scA[nf][2] - mnew);
                const float p3 = exp2f(scA[nf][3] - mnew);
                rs += (p0 + p1) + (p2 + p3);
                uint2 pw;
                pw.x = (unsigned)f2h(p0) | ((unsigned)f2h(p1) << 16);
                pw.y = (unsigned)f2h(p2) | ((unsigned)f2h(p3) << 16);
                *(uint2*)&Ps[rowA + nf * 16 + 4 * g] = pw;
            }
            rs += __shfl_xor(rs, 16);
            rs += __shfl_xor(rs, 32);
            lA = lA * fac + rs;
            mA = mnew;
            #pragma unroll
            for (int nf = 0; nf < 4; ++nf) {
                accA[nf][0] *= fac; accA[nf][1] *= fac;
                accA[nf][2] *= fac; accA[nf][3] *= fac;
            }
        }
        // ------- half B softmax -------
        {
            float mx = -1e30f;
            #pragma unroll
            for (int nf = 0; nf < 4; ++nf)
                #pragma unroll
                for (int e = 0; e < 4; ++e) {
                    float v = scB[nf][e] * scale2;
                    if (k0 + nf * 16 + 4 * g + e > qb) v = -1.0e9f;
                    scB[nf][e] = v;
                    mx = fmaxf(mx, v);
                }
            mx = fmaxf(mx, __shfl_xor(mx, 16));
            mx = fmaxf(mx, __shfl_xor(mx, 32));
            const float mnew = fmaxf(mB, mx);
            const float fac = exp2f(mB - mnew);
            float rs = 0.f;
            #pragma unroll
            for (int nf = 0; nf < 4; ++nf) {
                const float p0 = exp2f(scB[nf][0] - mnew);
                const float p1 = exp2f(scB[nf][1] - mnew);
                const float p2 = exp2f(scB[nf][2] - mnew);
                const float p3 = exp2f(scB[nf][3] - mnew);
                rs += (p0 + p1) + (p2 + p3);
                uint2 pw;
                pw.x = (unsigned)f2h(p0) | ((unsigned)f2h(p1) << 16);
                pw.y = (unsigned)f2h(p2) | ((unsigned)f2h(p3) << 16);
                *(uint2*)&Ps[rowB + nf * 16 + 4 * g] = pw;
            }
            rs += __shfl_xor(rs, 16);
            rs += __shfl_xor(rs, 32);
            lB = lB * fac + rs;
            mB = mnew;
            #pragma unroll
            for (int nf = 0; nf < 4; ++nf) {
                accB[nf][0] *= fac; accB[nf][1] *= fac;
                accB[nf][2] *= fac; accB[nf][3] *= fac;
            }
        }

        // ------- merged PV: V^T frags read once, used for both halves -------
        f16x8 bpA[2], bpB[2];
        #pragma unroll
        for (int ks = 0; ks < 2; ++ks) {
            bpA[ks] = *(const f16x8*)&Ps[rowA + ks * 32 + g * 8];
            bpB[ks] = *(const f16x8*)&Ps[rowB + ks * 32 + g * 8];
        }
        #pragma unroll
        for (int nf = 0; nf < 4; ++nf) {
            #pragma unroll
            for (int ks = 0; ks < 2; ++ks) {
                const f16x8 av = *(const f16x8*)&Vs[(nf * 16 + r) * 72 + ks * 32 + g * 8];
                accA[nf] = __builtin_amdgcn_mfma_f32_16x16x32_f16(av, bpA[ks], accA[nf], 0, 0, 0);
                accB[nf] = __builtin_amdgcn_mfma_f32_16x16x32_f16(av, bpB[ks], accB[nf], 0, 0, 0);
            }
        }
        __syncthreads();   // all reads done before next tile's LDS write
    }

    // epilogue: accX[nf][e] = O[qx][d = nf*16 + 4g + e]
    const float invA = 1.0f / lA;
    const float invB = 1.0f / lB;
    unsigned short* obA = out + ((size_t)b * 2048 + qa) * 1024 + h * 64;
    unsigned short* obB = out + ((size_t)b * 2048 + qb) * 1024 + h * 64;
    #pragma unroll
    for (int nf = 0; nf < 4; ++nf) {
        ushort4 oA, oB;
        oA.x = f2h(accA[nf][0] * invA); oA.y = f2h(accA[nf][1] * invA);
        oA.z = f2h(accA[nf][2] * invA); oA.w = f2h(accA[nf][3] * invA);
        oB.x = f2h(accB[nf][0] * invB); oB.y = f2h(accB[nf][1] * invB);
        oB.z = f2h(accB[nf][2] * invB); oB.w = f2h(accB[nf][3] * invB);
        *(ushort4*)(obA + nf * 16 + 4 * g) = oA;
        *(ushort4*)(obB + nf * 16 + 4 * g) = oB;
    }
}

// ---------------------------------------------------------------------------
extern "C" void kernel_launch(void* const* d_in, const int* in_sizes, int n_in,
                              void* d_out, int out_size, void* d_ws, size_t ws_size,
                              hipStream_t stream)
{
    const float* x   = (const float*)d_in[0];
    // d_in[1] = mask (deterministic causal; unused)
    const float* Wkv = (const float*)d_in[2];
    const float* bkv = (const float*)d_in[3];
    const float* Wq  = (const float*)d_in[4];
    const float* bq  = (const float*)d_in[5];
    const float* Wku = (const float*)d_in[6];
    const float* bku = (const float*)d_in[7];
    const float* Wvu = (const float*)d_in[8];
    const float* bvu = (const float*)d_in[9];
    const float* Wqu = (const float*)d_in[10];
    const float* bqu = (const float*)d_in[11];
    const float* Wkr = (const float*)d_in[12];
    const float* bkr = (const float*)d_in[13];
    const float* Wqr = (const float*)d_in[14];
    const float* bqr = (const float*)d_in[15];
    const float* Wo  = (const float*)d_in[16];
    const float* bo  = (const float*)d_in[17];
    float* out = (float*)d_out;

    unsigned short* ws = (unsigned short*)d_ws;
    unsigned short* x_f    = ws;                                    // 4096*1024
    unsigned short* wkv_f  = x_f    + (size_t)4096 * 1024;
    unsigned short* wq_f   = wkv_f  + (size_t)256 * 1024;
    unsigned short* wku_f  = wq_f   + (size_t)512 * 1024;
    unsigned short* wvu_f  = wku_f  + (size_t)1024 * 256;
    unsigned short* wqu_f  = wvu_f  + (size_t)1024 * 256;
    unsigned short* wkr_f  = wqu_f  + (size_t)1024 * 512;
    unsigned short* wqr_f  = wkr_f  + (size_t)64 * 1024;
    unsigned short* wo_f   = wqr_f  + (size_t)1024 * 512;
    unsigned short* c_vk   = wo_f   + (size_t)1024 * 1024;          // 4096*256
    unsigned short* c_q    = c_vk   + (size_t)4096 * 256;           // 4096*512
    unsigned short* q_full = c_q    + (size_t)4096 * 512;           // (B*H,S,128)
    unsigned short* k_head = q_full + (size_t)32 * 2048 * 128;      // (B*H,S,64)
    unsigned short* k_rope = k_head + (size_t)32 * 2048 * 64;       // (B,S,64)
    unsigned short* v_t    = k_rope + (size_t)2 * 2048 * 64;        // (B*H,64,S)
    unsigned short* attn_o = v_t    + (size_t)32 * 64 * 2048;       // (B,S,1024)

    CJobs js;
    js.src[0] = x;   js.dst[0] = x_f;   js.n4[0] = 4096 * 1024 / 4;
    js.src[1] = Wkv; js.dst[1] = wkv_f; js.n4[1] = 256 * 1024 / 4;
    js.src[2] = Wq;  js.dst[2] = wq_f;  js.n4[2] = 512 * 1024 / 4;
    js.src[3] = Wku; js.dst[3] = wku_f; js.n4[3] = 1024 * 256 / 4;
    js.src[4] = Wvu; js.dst[4] = wvu_f; js.n4[4] = 1024 * 256 / 4;
    js.src[5] = Wqu; js.dst[5] = wqu_f; js.n4[5] = 1024 * 512 / 4;
    js.src[6] = Wkr; js.dst[6] = wkr_f; js.n4[6] = 64 * 1024 / 4;
    js.src[7] = Wqr; js.dst[7] = wqr_f; js.n4[7] = 1024 * 512 / 4;
    js.src[8] = Wo;  js.dst[8] = wo_f;  js.n4[8] = 1024 * 1024 / 4;
    convert_f16<<<dim3(64, 9), 256, 0, stream>>>(js);

    // latent projections (64-tile, 2 waves, 832 blocks)
    gemm_latent<<<dim3(13, 64), 128, 0, stream>>>(x_f, wkv_f, bkv, wq_f, bq, wkr_f, bkr,
                                                  c_vk, c_q, k_rope);

    // K/V up-projection: [Wku | Wvu], K=256; k_head + v_t epilogues
    gemm128<0><<<dim3(16, 32), 256, 0, stream>>>(c_vk, wku_f, bku, wvu_f, bvu,
                                                 k_head, v_t, 256, 8);
    // Q up-projection: [Wqu | Wqr(rope)], K=512; both into q_full
    gemm128<2><<<dim3(16, 32), 256, 0, stream>>>(c_q, wqu_f, bqu, wqr_f, bqr,
                                                 q_full, nullptr, 512, 8);

    // causal flash attention (MFMA, swapped operands, 32 q/wave, balanced)
    attn_mfma<<<dim3(16, 32), 256, 0, stream>>>(q_full, k_head, k_rope, v_t, attn_o);

    // output projection -> f32 d_out
    gemm128<4><<<dim3(8, 32), 256, 0, stream>>>(attn_o, wo_f, bo, nullptr, nullptr,
                                                out, nullptr, 1024, 8);
}